// Round 1
// baseline (3540.680 us; speedup 1.0000x reference)
//
#include <hip/hip_runtime.h>

#define EPS_LEN   1e-20f
#define EPS_DENOM 1e-6f

// ---------------------------------------------------------------------------
// Kernel 1: per-face — compute face normal + tangent, scatter-add to vertices.
// nacc/tacc are V*3 fp32 accumulators (zeroed before launch).
// ---------------------------------------------------------------------------
__global__ void vg_face_kernel(const float* __restrict__ pos,
                               const int*   __restrict__ faces,
                               const float* __restrict__ tex,
                               const int*   __restrict__ uvf,
                               float* __restrict__ nacc,
                               float* __restrict__ tacc,
                               int F) {
    int f = blockIdx.x * blockDim.x + threadIdx.x;
    if (f >= F) return;

    const int i0 = faces[3 * f + 0];
    const int i1 = faces[3 * f + 1];
    const int i2 = faces[3 * f + 2];

    const float p0x = pos[3 * i0 + 0], p0y = pos[3 * i0 + 1], p0z = pos[3 * i0 + 2];
    const float p1x = pos[3 * i1 + 0], p1y = pos[3 * i1 + 1], p1z = pos[3 * i1 + 2];
    const float p2x = pos[3 * i2 + 0], p2y = pos[3 * i2 + 1], p2z = pos[3 * i2 + 2];

    // pe1 = p1 - p0, pe2 = p2 - p0
    const float e1x = p1x - p0x, e1y = p1y - p0y, e1z = p1z - p0z;
    const float e2x = p2x - p0x, e2y = p2y - p0y, e2z = p2z - p0z;

    // face normal = cross(e1, e2)
    const float nx = e1y * e2z - e1z * e2y;
    const float ny = e1z * e2x - e1x * e2z;
    const float nz = e1x * e2y - e1y * e2x;

    // UV edges
    const int t0 = uvf[3 * f + 0];
    const int t1 = uvf[3 * f + 1];
    const int t2 = uvf[3 * f + 2];

    const float u0x = tex[2 * t0 + 0], u0y = tex[2 * t0 + 1];
    const float u1x = tex[2 * t1 + 0], u1y = tex[2 * t1 + 1];
    const float u2x = tex[2 * t2 + 0], u2y = tex[2 * t2 + 1];

    const float d1x = u1x - u0x, d1y = u1y - u0y;   // uve1
    const float d2x = u2x - u0x, d2y = u2y - u0y;   // uve2

    float denom = d1x * d2y - d1y * d2x;
    denom = (denom > 0.0f) ? fmaxf(denom, EPS_DENOM) : fminf(denom, -EPS_DENOM);
    const float inv = 1.0f / denom;

    // nom = pe1 * uve2.y - pe2 * uve1.y ; tang = nom / denom
    const float tx = (e1x * d2y - e2x * d1y) * inv;
    const float ty = (e1y * d2y - e2y * d1y) * inv;
    const float tz = (e1z * d2y - e2z * d1y) * inv;

    // scatter-add face normal to its 3 vertices
    atomicAdd(&nacc[3 * i0 + 0], nx);
    atomicAdd(&nacc[3 * i0 + 1], ny);
    atomicAdd(&nacc[3 * i0 + 2], nz);
    atomicAdd(&nacc[3 * i1 + 0], nx);
    atomicAdd(&nacc[3 * i1 + 1], ny);
    atomicAdd(&nacc[3 * i1 + 2], nz);
    atomicAdd(&nacc[3 * i2 + 0], nx);
    atomicAdd(&nacc[3 * i2 + 1], ny);
    atomicAdd(&nacc[3 * i2 + 2], nz);

    // scatter-add tangent to its 3 vertices (indexed by faces, not uv_faces!)
    atomicAdd(&tacc[3 * i0 + 0], tx);
    atomicAdd(&tacc[3 * i0 + 1], ty);
    atomicAdd(&tacc[3 * i0 + 2], tz);
    atomicAdd(&tacc[3 * i1 + 0], tx);
    atomicAdd(&tacc[3 * i1 + 1], ty);
    atomicAdd(&tacc[3 * i1 + 2], tz);
    atomicAdd(&tacc[3 * i2 + 0], tx);
    atomicAdd(&tacc[3 * i2 + 1], ty);
    atomicAdd(&tacc[3 * i2 + 2], tz);
}

// ---------------------------------------------------------------------------
// Kernel 2: per-vertex — default + normalize normal; normalize, orthogonalize,
// re-normalize tangent. In-place on the accumulators (which live in d_out).
// ---------------------------------------------------------------------------
__global__ void vg_finalize_kernel(float* __restrict__ nacc,
                                   float* __restrict__ tacc,
                                   int V) {
    int v = blockIdx.x * blockDim.x + threadIdx.x;
    if (v >= V) return;

    float nx = nacc[3 * v + 0];
    float ny = nacc[3 * v + 1];
    float nz = nacc[3 * v + 2];

    float nd = nx * nx + ny * ny + nz * nz;
    if (nd > EPS_LEN) {
        const float inv = 1.0f / sqrtf(nd);   // nd > EPS_LEN so max() is a no-op
        nx *= inv; ny *= inv; nz *= inv;
    } else {
        nx = 0.0f; ny = 0.0f; nz = 1.0f;      // default, already unit length
    }

    float tx = tacc[3 * v + 0];
    float ty = tacc[3 * v + 1];
    float tz = tacc[3 * v + 2];

    // safe_normalize(t)
    float td = tx * tx + ty * ty + tz * tz;
    float invt = 1.0f / sqrtf(fmaxf(td, EPS_LEN));
    tx *= invt; ty *= invt; tz *= invt;

    // t -= dot(t, n) * n
    const float dp = tx * nx + ty * ny + tz * nz;
    tx -= dp * nx; ty -= dp * ny; tz -= dp * nz;

    // safe_normalize again
    float td2 = tx * tx + ty * ty + tz * tz;
    float invt2 = 1.0f / sqrtf(fmaxf(td2, EPS_LEN));
    tx *= invt2; ty *= invt2; tz *= invt2;

    nacc[3 * v + 0] = nx;
    nacc[3 * v + 1] = ny;
    nacc[3 * v + 2] = nz;
    tacc[3 * v + 0] = tx;
    tacc[3 * v + 1] = ty;
    tacc[3 * v + 2] = tz;
}

extern "C" void kernel_launch(void* const* d_in, const int* in_sizes, int n_in,
                              void* d_out, int out_size, void* d_ws, size_t ws_size,
                              hipStream_t stream) {
    const float* pos   = (const float*)d_in[0];
    const int*   faces = (const int*)  d_in[1];
    const float* tex   = (const float*)d_in[2];
    const int*   uvf   = (const int*)  d_in[3];

    const int V = in_sizes[0] / 3;
    const int F = in_sizes[1] / 3;

    float* out  = (float*)d_out;
    float* nacc = out;                    // output[0] : normals  (V,3)
    float* tacc = out + (size_t)3 * V;    // output[1] : tangents (V,3)

    // zero the accumulators (d_out is not re-zeroed between timed replays)
    hipMemsetAsync(d_out, 0, (size_t)out_size * sizeof(float), stream);

    const int BLK = 256;
    vg_face_kernel<<<(F + BLK - 1) / BLK, BLK, 0, stream>>>(pos, faces, tex, uvf,
                                                            nacc, tacc, F);
    vg_finalize_kernel<<<(V + BLK - 1) / BLK, BLK, 0, stream>>>(nacc, tacc, V);
}

// Round 2
// 1933.728 us; speedup vs baseline: 1.8310x; 1.8310x over previous
//
#include <hip/hip_runtime.h>

#define EPS_LEN   1e-20f
#define EPS_DENOM 1e-6f

#define VB_LOG    10                 // 1024 vertices per bucket
#define VB        (1 << VB_LOG)
#define CAP       8192               // entry capacity per bucket (mean load ~6144)
#define FSTRIDE   8                  // floats per face record (32B, float4-aligned)

// ---------------------------------------------------------------------------
// Kernel A: per-face. Compute face normal + tangent, write face record,
// place 3 corner entries into vertex-range buckets via cursor atomics.
// Overflow (slot >= CAP) falls back to direct global atomics into out accums.
// ---------------------------------------------------------------------------
__global__ void vg_face_scatter(const float* __restrict__ pos,
                                const int*   __restrict__ faces,
                                const float* __restrict__ tex,
                                const int*   __restrict__ uvf,
                                float*       __restrict__ face_data,
                                unsigned*    __restrict__ entries,
                                int*         __restrict__ cursors,
                                float*       __restrict__ nacc,
                                float*       __restrict__ tacc,
                                int F) {
    int f = blockIdx.x * blockDim.x + threadIdx.x;
    if (f >= F) return;

    const int i0 = faces[3 * f + 0];
    const int i1 = faces[3 * f + 1];
    const int i2 = faces[3 * f + 2];

    const float p0x = pos[3 * i0 + 0], p0y = pos[3 * i0 + 1], p0z = pos[3 * i0 + 2];
    const float p1x = pos[3 * i1 + 0], p1y = pos[3 * i1 + 1], p1z = pos[3 * i1 + 2];
    const float p2x = pos[3 * i2 + 0], p2y = pos[3 * i2 + 1], p2z = pos[3 * i2 + 2];

    const float e1x = p1x - p0x, e1y = p1y - p0y, e1z = p1z - p0z;
    const float e2x = p2x - p0x, e2y = p2y - p0y, e2z = p2z - p0z;

    // face normal = cross(e1, e2)
    const float nx = e1y * e2z - e1z * e2y;
    const float ny = e1z * e2x - e1x * e2z;
    const float nz = e1x * e2y - e1y * e2x;

    const int t0 = uvf[3 * f + 0];
    const int t1 = uvf[3 * f + 1];
    const int t2 = uvf[3 * f + 2];

    const float u0x = tex[2 * t0 + 0], u0y = tex[2 * t0 + 1];
    const float u1x = tex[2 * t1 + 0], u1y = tex[2 * t1 + 1];
    const float u2x = tex[2 * t2 + 0], u2y = tex[2 * t2 + 1];

    const float d1x = u1x - u0x, d1y = u1y - u0y;
    const float d2x = u2x - u0x, d2y = u2y - u0y;

    float denom = d1x * d2y - d1y * d2x;
    denom = (denom > 0.0f) ? fmaxf(denom, EPS_DENOM) : fminf(denom, -EPS_DENOM);
    const float inv = 1.0f / denom;

    const float tx = (e1x * d2y - e2x * d1y) * inv;
    const float ty = (e1y * d2y - e2y * d1y) * inv;
    const float tz = (e1z * d2y - e2z * d1y) * inv;

    // face record: [nx ny nz tx | ty tz . .]  (two aligned float4 stores)
    float4 ra = make_float4(nx, ny, nz, tx);
    float4 rb = make_float4(ty, tz, 0.0f, 0.0f);
    *reinterpret_cast<float4*>(&face_data[(size_t)f * FSTRIDE])     = ra;
    *reinterpret_cast<float4*>(&face_data[(size_t)f * FSTRIDE + 4]) = rb;

    const int vi[3] = { i0, i1, i2 };
#pragma unroll
    for (int c = 0; c < 3; ++c) {
        const int v = vi[c];
        const int b = v >> VB_LOG;
        const int slot = atomicAdd(&cursors[b], 1);
        if (slot < CAP) {
            entries[(size_t)b * CAP + slot] =
                ((unsigned)(v & (VB - 1)) << 22) | (unsigned)f;
        } else {
            // overflow fallback: direct global atomics (rare/never)
            atomicAdd(&nacc[3 * v + 0], nx);
            atomicAdd(&nacc[3 * v + 1], ny);
            atomicAdd(&nacc[3 * v + 2], nz);
            atomicAdd(&tacc[3 * v + 0], tx);
            atomicAdd(&tacc[3 * v + 1], ty);
            atomicAdd(&tacc[3 * v + 2], tz);
        }
    }
}

// ---------------------------------------------------------------------------
// Kernel B: per bucket. Accumulate entries into LDS (ds_add_f32), then
// finalize (normalize normal, orthonormalize tangent) fused into writeback.
// Adds the (memset-zero + overflow) global partial before finalizing.
// ---------------------------------------------------------------------------
__global__ __launch_bounds__(256)
void vg_bucket_accum(const float*    __restrict__ face_data,
                     const unsigned* __restrict__ entries,
                     const int*      __restrict__ cursors,
                     float*          __restrict__ nacc,
                     float*          __restrict__ tacc,
                     int V) {
    __shared__ float acc[VB * 6];   // 24 KB

    const int b = blockIdx.x;

    for (int i = threadIdx.x; i < VB * 6; i += 256) acc[i] = 0.0f;
    __syncthreads();

    int count = cursors[b];
    if (count > CAP) count = CAP;
    const unsigned* eb = entries + (size_t)b * CAP;

    for (int e = threadIdx.x; e < count; e += 256) {
        const unsigned ent = eb[e];
        const int vloc = (int)(ent >> 22);
        const int f    = (int)(ent & 0x3FFFFFu);
        const float4 ra = *reinterpret_cast<const float4*>(&face_data[(size_t)f * FSTRIDE]);
        const float4 rb = *reinterpret_cast<const float4*>(&face_data[(size_t)f * FSTRIDE + 4]);
        float* a = &acc[vloc * 6];
        atomicAdd(&a[0], ra.x);
        atomicAdd(&a[1], ra.y);
        atomicAdd(&a[2], ra.z);
        atomicAdd(&a[3], ra.w);
        atomicAdd(&a[4], rb.x);
        atomicAdd(&a[5], rb.y);
    }
    __syncthreads();

    const int vbase = b << VB_LOG;
    for (int vloc = threadIdx.x; vloc < VB; vloc += 256) {
        const int v = vbase + vloc;
        if (v >= V) break;

        // total = overflow partial (global) + bucket sum (LDS)
        float nx = nacc[3 * v + 0] + acc[vloc * 6 + 0];
        float ny = nacc[3 * v + 1] + acc[vloc * 6 + 1];
        float nz = nacc[3 * v + 2] + acc[vloc * 6 + 2];
        float tx = tacc[3 * v + 0] + acc[vloc * 6 + 3];
        float ty = tacc[3 * v + 1] + acc[vloc * 6 + 4];
        float tz = tacc[3 * v + 2] + acc[vloc * 6 + 5];

        const float nd = nx * nx + ny * ny + nz * nz;
        if (nd > EPS_LEN) {
            const float invn = 1.0f / sqrtf(nd);
            nx *= invn; ny *= invn; nz *= invn;
        } else {
            nx = 0.0f; ny = 0.0f; nz = 1.0f;
        }

        const float td = tx * tx + ty * ty + tz * tz;
        const float invt = 1.0f / sqrtf(fmaxf(td, EPS_LEN));
        tx *= invt; ty *= invt; tz *= invt;

        const float dp = tx * nx + ty * ny + tz * nz;
        tx -= dp * nx; ty -= dp * ny; tz -= dp * nz;

        const float td2 = tx * tx + ty * ty + tz * tz;
        const float invt2 = 1.0f / sqrtf(fmaxf(td2, EPS_LEN));
        tx *= invt2; ty *= invt2; tz *= invt2;

        nacc[3 * v + 0] = nx;
        nacc[3 * v + 1] = ny;
        nacc[3 * v + 2] = nz;
        tacc[3 * v + 0] = tx;
        tacc[3 * v + 1] = ty;
        tacc[3 * v + 2] = tz;
    }
}

// ---------------------------------------------------------------------------
// Fallback path (round-1 proven kernels) if ws is too small / sizes odd.
// ---------------------------------------------------------------------------
__global__ void vg_face_kernel(const float* __restrict__ pos,
                               const int*   __restrict__ faces,
                               const float* __restrict__ tex,
                               const int*   __restrict__ uvf,
                               float* __restrict__ nacc,
                               float* __restrict__ tacc,
                               int F) {
    int f = blockIdx.x * blockDim.x + threadIdx.x;
    if (f >= F) return;

    const int i0 = faces[3 * f + 0];
    const int i1 = faces[3 * f + 1];
    const int i2 = faces[3 * f + 2];

    const float p0x = pos[3 * i0 + 0], p0y = pos[3 * i0 + 1], p0z = pos[3 * i0 + 2];
    const float p1x = pos[3 * i1 + 0], p1y = pos[3 * i1 + 1], p1z = pos[3 * i1 + 2];
    const float p2x = pos[3 * i2 + 0], p2y = pos[3 * i2 + 1], p2z = pos[3 * i2 + 2];

    const float e1x = p1x - p0x, e1y = p1y - p0y, e1z = p1z - p0z;
    const float e2x = p2x - p0x, e2y = p2y - p0y, e2z = p2z - p0z;

    const float nx = e1y * e2z - e1z * e2y;
    const float ny = e1z * e2x - e1x * e2z;
    const float nz = e1x * e2y - e1y * e2x;

    const int t0 = uvf[3 * f + 0];
    const int t1 = uvf[3 * f + 1];
    const int t2 = uvf[3 * f + 2];

    const float u0x = tex[2 * t0 + 0], u0y = tex[2 * t0 + 1];
    const float u1x = tex[2 * t1 + 0], u1y = tex[2 * t1 + 1];
    const float u2x = tex[2 * t2 + 0], u2y = tex[2 * t2 + 1];

    const float d1x = u1x - u0x, d1y = u1y - u0y;
    const float d2x = u2x - u0x, d2y = u2y - u0y;

    float denom = d1x * d2y - d1y * d2x;
    denom = (denom > 0.0f) ? fmaxf(denom, EPS_DENOM) : fminf(denom, -EPS_DENOM);
    const float inv = 1.0f / denom;

    const float tx = (e1x * d2y - e2x * d1y) * inv;
    const float ty = (e1y * d2y - e2y * d1y) * inv;
    const float tz = (e1z * d2y - e2z * d1y) * inv;

    atomicAdd(&nacc[3 * i0 + 0], nx); atomicAdd(&nacc[3 * i0 + 1], ny); atomicAdd(&nacc[3 * i0 + 2], nz);
    atomicAdd(&nacc[3 * i1 + 0], nx); atomicAdd(&nacc[3 * i1 + 1], ny); atomicAdd(&nacc[3 * i1 + 2], nz);
    atomicAdd(&nacc[3 * i2 + 0], nx); atomicAdd(&nacc[3 * i2 + 1], ny); atomicAdd(&nacc[3 * i2 + 2], nz);
    atomicAdd(&tacc[3 * i0 + 0], tx); atomicAdd(&tacc[3 * i0 + 1], ty); atomicAdd(&tacc[3 * i0 + 2], tz);
    atomicAdd(&tacc[3 * i1 + 0], tx); atomicAdd(&tacc[3 * i1 + 1], ty); atomicAdd(&tacc[3 * i1 + 2], tz);
    atomicAdd(&tacc[3 * i2 + 0], tx); atomicAdd(&tacc[3 * i2 + 1], ty); atomicAdd(&tacc[3 * i2 + 2], tz);
}

__global__ void vg_finalize_kernel(float* __restrict__ nacc,
                                   float* __restrict__ tacc,
                                   int V) {
    int v = blockIdx.x * blockDim.x + threadIdx.x;
    if (v >= V) return;

    float nx = nacc[3 * v + 0], ny = nacc[3 * v + 1], nz = nacc[3 * v + 2];
    float nd = nx * nx + ny * ny + nz * nz;
    if (nd > EPS_LEN) {
        const float invn = 1.0f / sqrtf(nd);
        nx *= invn; ny *= invn; nz *= invn;
    } else {
        nx = 0.0f; ny = 0.0f; nz = 1.0f;
    }

    float tx = tacc[3 * v + 0], ty = tacc[3 * v + 1], tz = tacc[3 * v + 2];
    float td = tx * tx + ty * ty + tz * tz;
    float invt = 1.0f / sqrtf(fmaxf(td, EPS_LEN));
    tx *= invt; ty *= invt; tz *= invt;
    const float dp = tx * nx + ty * ny + tz * nz;
    tx -= dp * nx; ty -= dp * ny; tz -= dp * nz;
    float td2 = tx * tx + ty * ty + tz * tz;
    float invt2 = 1.0f / sqrtf(fmaxf(td2, EPS_LEN));
    tx *= invt2; ty *= invt2; tz *= invt2;

    nacc[3 * v + 0] = nx; nacc[3 * v + 1] = ny; nacc[3 * v + 2] = nz;
    tacc[3 * v + 0] = tx; tacc[3 * v + 1] = ty; tacc[3 * v + 2] = tz;
}

extern "C" void kernel_launch(void* const* d_in, const int* in_sizes, int n_in,
                              void* d_out, int out_size, void* d_ws, size_t ws_size,
                              hipStream_t stream) {
    const float* pos   = (const float*)d_in[0];
    const int*   faces = (const int*)  d_in[1];
    const float* tex   = (const float*)d_in[2];
    const int*   uvf   = (const int*)  d_in[3];

    const int V = in_sizes[0] / 3;
    const int F = in_sizes[1] / 3;

    float* out  = (float*)d_out;
    float* nacc = out;                    // output[0] : normals  (V,3)
    float* tacc = out + (size_t)3 * V;    // output[1] : tangents (V,3)

    const int BLK = 256;
    const int NB  = (V + VB - 1) >> VB_LOG;

    // workspace layout
    const size_t face_bytes   = (size_t)F * FSTRIDE * sizeof(float);
    const size_t entry_bytes  = (size_t)NB * CAP * sizeof(unsigned);
    const size_t cursor_bytes = (size_t)NB * sizeof(int);
    const size_t need = face_bytes + entry_bytes + cursor_bytes + 256;

    hipMemsetAsync(d_out, 0, (size_t)out_size * sizeof(float), stream);

    if (ws_size < need || F > (1 << 22)) {
        // fallback: proven global-atomic path
        vg_face_kernel<<<(F + BLK - 1) / BLK, BLK, 0, stream>>>(pos, faces, tex, uvf,
                                                                nacc, tacc, F);
        vg_finalize_kernel<<<(V + BLK - 1) / BLK, BLK, 0, stream>>>(nacc, tacc, V);
        return;
    }

    char* ws = (char*)d_ws;
    float*    face_data = (float*)ws;
    unsigned* entries   = (unsigned*)(ws + face_bytes);
    int*      cursors   = (int*)(ws + face_bytes + entry_bytes);

    hipMemsetAsync(cursors, 0, cursor_bytes, stream);

    vg_face_scatter<<<(F + BLK - 1) / BLK, BLK, 0, stream>>>(
        pos, faces, tex, uvf, face_data, entries, cursors, nacc, tacc, F);

    vg_bucket_accum<<<NB, BLK, 0, stream>>>(
        face_data, entries, cursors, nacc, tacc, V);
}

// Round 3
// 937.338 us; speedup vs baseline: 3.7774x; 2.0630x over previous
//
#include <hip/hip_runtime.h>

#define EPS_LEN   1e-20f
#define EPS_DENOM 1e-6f

#define CB_LOG   13
#define CB       (1 << CB_LOG)      // 8192 vertices per coarse bucket
#define QLOG     11
#define QSIZE    (1 << QLOG)        // 2048 vertices per LDS accumulation pass
#define CAP_C    57344              // per-bucket entry capacity (mean 49152)
#define FST      6                  // floats per face record (24B)
#define BLKA     1024
#define MAXB     256

// ---------------------------------------------------------------------------
// Kernel A: per-face compute + block-coalesced binning into coarse buckets.
// ---------------------------------------------------------------------------
__global__ __launch_bounds__(BLKA)
void vg_face_bin(const float* __restrict__ pos, const int* __restrict__ faces,
                 const float* __restrict__ tex, const int* __restrict__ uvf,
                 float* __restrict__ face_data,
                 unsigned* __restrict__ ef, unsigned short* __restrict__ ev,
                 int* __restrict__ cursors, int* __restrict__ validw,
                 float* __restrict__ nacc, float* __restrict__ tacc,
                 int F, int NBC)
{
    __shared__ int h[MAXB], sc[MAXB], loff[MAXB], lfill[MAXB], gbase[MAXB];
    __shared__ unsigned       sface[3 * BLKA];
    __shared__ unsigned short svloc[3 * BLKA];
    __shared__ unsigned char  sbuck[3 * BLKA];

    const int t = threadIdx.x;
    const int f = blockIdx.x * BLKA + t;

    if (t < MAXB) { h[t] = 0; lfill[t] = 0; }
    for (int i = t; i < 3 * BLKA; i += BLKA) sbuck[i] = 0xFF;
    __syncthreads();

    const bool on = (f < F);
    int i0 = 0, i1 = 0, i2 = 0;
    float nx = 0, ny = 0, nz = 0, txv = 0, tyv = 0, tzv = 0;

    if (on) {
        i0 = faces[3 * f + 0]; i1 = faces[3 * f + 1]; i2 = faces[3 * f + 2];

        const float p0x = pos[3*i0+0], p0y = pos[3*i0+1], p0z = pos[3*i0+2];
        const float p1x = pos[3*i1+0], p1y = pos[3*i1+1], p1z = pos[3*i1+2];
        const float p2x = pos[3*i2+0], p2y = pos[3*i2+1], p2z = pos[3*i2+2];

        const float e1x = p1x - p0x, e1y = p1y - p0y, e1z = p1z - p0z;
        const float e2x = p2x - p0x, e2y = p2y - p0y, e2z = p2z - p0z;

        nx = e1y * e2z - e1z * e2y;
        ny = e1z * e2x - e1x * e2z;
        nz = e1x * e2y - e1y * e2x;

        const int t0 = uvf[3 * f + 0];
        const int t1 = uvf[3 * f + 1];
        const int t2 = uvf[3 * f + 2];

        const float u0x = tex[2*t0+0], u0y = tex[2*t0+1];
        const float u1x = tex[2*t1+0], u1y = tex[2*t1+1];
        const float u2x = tex[2*t2+0], u2y = tex[2*t2+1];

        const float d1x = u1x - u0x, d1y = u1y - u0y;
        const float d2x = u2x - u0x, d2y = u2y - u0y;

        float denom = d1x * d2y - d1y * d2x;
        denom = (denom > 0.0f) ? fmaxf(denom, EPS_DENOM) : fminf(denom, -EPS_DENOM);
        const float inv = 1.0f / denom;

        txv = (e1x * d2y - e2x * d1y) * inv;
        tyv = (e1y * d2y - e2y * d1y) * inv;
        tzv = (e1z * d2y - e2z * d1y) * inv;

        float* fd = &face_data[(size_t)f * FST];
        reinterpret_cast<float2*>(fd)[0] = make_float2(nx, ny);
        reinterpret_cast<float2*>(fd)[1] = make_float2(nz, txv);
        reinterpret_cast<float2*>(fd)[2] = make_float2(tyv, tzv);

        atomicAdd(&h[i0 >> CB_LOG], 1);
        atomicAdd(&h[i1 >> CB_LOG], 1);
        atomicAdd(&h[i2 >> CB_LOG], 1);
    }
    __syncthreads();

    // exclusive scan of h over MAXB elements (Hillis-Steele)
    if (t < MAXB) sc[t] = h[t];
    __syncthreads();
    for (int d = 1; d < MAXB; d <<= 1) {
        int v2 = 0;
        if (t < MAXB) v2 = sc[t] + ((t >= d) ? sc[t - d] : 0);
        __syncthreads();
        if (t < MAXB) sc[t] = v2;
        __syncthreads();
    }
    if (t < MAXB) {
        loff[t] = sc[t] - h[t];
        const int cnt = h[t];
        int gb = -1;
        if (t < NBC && cnt > 0) {
            gb = atomicAdd(&cursors[t], cnt);
            if (gb + cnt <= CAP_C) atomicMax(&validw[t], gb + cnt);
            else gb = -1;                       // chunk overflow: whole chunk falls back
        }
        gbase[t] = gb;
    }
    __syncthreads();

    // stage entries (or rare global-atomic fallback)
    if (on) {
        const int vi[3] = { i0, i1, i2 };
#pragma unroll
        for (int c = 0; c < 3; ++c) {
            const int v = vi[c];
            const int b = v >> CB_LOG;
            if (gbase[b] >= 0) {
                const int slot = atomicAdd(&lfill[b], 1);
                const int p = loff[b] + slot;
                sface[p] = (unsigned)f;
                svloc[p] = (unsigned short)(v & (CB - 1));
                sbuck[p] = (unsigned char)b;
            } else {
                atomicAdd(&nacc[3*v+0], nx);
                atomicAdd(&nacc[3*v+1], ny);
                atomicAdd(&nacc[3*v+2], nz);
                atomicAdd(&tacc[3*v+0], txv);
                atomicAdd(&tacc[3*v+1], tyv);
                atomicAdd(&tacc[3*v+2], tzv);
            }
        }
    }
    __syncthreads();

    // coalesced copy-out: consecutive i in one bucket -> consecutive global slots
    for (int i = t; i < 3 * BLKA; i += BLKA) {
        const unsigned b = sbuck[i];
        if (b != 0xFFu) {
            const int g = gbase[b] + (i - loff[b]);
            const size_t base = (size_t)b * CAP_C;
            ef[base + g] = sface[i];
            ev[base + g] = svloc[i];
        }
    }
}

// ---------------------------------------------------------------------------
// Kernel B: one block per coarse bucket; 4 LDS passes of 2048 vertices.
// Streams ev (filter) + ef (matched), gathers 24B face records, LDS fp
// atomics, fused finalize.
// ---------------------------------------------------------------------------
__global__ __launch_bounds__(BLKA)
void vg_bucket_reduce(const float* __restrict__ face_data,
                      const unsigned* __restrict__ ef,
                      const unsigned short* __restrict__ ev,
                      const int* __restrict__ validw,
                      float* __restrict__ nacc, float* __restrict__ tacc,
                      int V)
{
    __shared__ float acc[QSIZE * 6];   // 48 KB
    const int b = blockIdx.x;
    const int t = threadIdx.x;
    int count = validw[b];
    if (count > CAP_C) count = CAP_C;
    const size_t ebase = (size_t)b * CAP_C;
    const int vbase = b << CB_LOG;

    for (int q = 0; q < 4; ++q) {
        for (int i = t; i < QSIZE * 6; i += BLKA) acc[i] = 0.0f;
        __syncthreads();

        for (int e = t; e < count; e += BLKA) {
            const int vloc = (int)ev[ebase + e];
            if ((vloc >> QLOG) == q) {
                const unsigned f = ef[ebase + e];
                const float* fd = &face_data[(size_t)f * FST];
                const float2 a0 = reinterpret_cast<const float2*>(fd)[0];
                const float2 a1 = reinterpret_cast<const float2*>(fd)[1];
                const float2 a2 = reinterpret_cast<const float2*>(fd)[2];
                float* a = &acc[(vloc & (QSIZE - 1)) * 6];
                atomicAdd(a + 0, a0.x);
                atomicAdd(a + 1, a0.y);
                atomicAdd(a + 2, a1.x);
                atomicAdd(a + 3, a1.y);
                atomicAdd(a + 4, a2.x);
                atomicAdd(a + 5, a2.y);
            }
        }
        __syncthreads();

        for (int i = t; i < QSIZE; i += BLKA) {
            const int v = vbase + (q << QLOG) + i;
            if (v < V) {
                float nx = nacc[3*v+0] + acc[i*6+0];
                float ny = nacc[3*v+1] + acc[i*6+1];
                float nz = nacc[3*v+2] + acc[i*6+2];
                float tx = tacc[3*v+0] + acc[i*6+3];
                float ty = tacc[3*v+1] + acc[i*6+4];
                float tz = tacc[3*v+2] + acc[i*6+5];

                const float nd = nx*nx + ny*ny + nz*nz;
                if (nd > EPS_LEN) {
                    const float invn = 1.0f / sqrtf(nd);
                    nx *= invn; ny *= invn; nz *= invn;
                } else {
                    nx = 0.0f; ny = 0.0f; nz = 1.0f;
                }

                const float td = tx*tx + ty*ty + tz*tz;
                const float invt = 1.0f / sqrtf(fmaxf(td, EPS_LEN));
                tx *= invt; ty *= invt; tz *= invt;

                const float dp = tx*nx + ty*ny + tz*nz;
                tx -= dp * nx; ty -= dp * ny; tz -= dp * nz;

                const float td2 = tx*tx + ty*ty + tz*tz;
                const float invt2 = 1.0f / sqrtf(fmaxf(td2, EPS_LEN));
                tx *= invt2; ty *= invt2; tz *= invt2;

                nacc[3*v+0] = nx; nacc[3*v+1] = ny; nacc[3*v+2] = nz;
                tacc[3*v+0] = tx; tacc[3*v+1] = ty; tacc[3*v+2] = tz;
            }
        }
        __syncthreads();
    }
}

// ---------------------------------------------------------------------------
// Fallback path (round-1 proven kernels) if ws too small / sizes odd.
// ---------------------------------------------------------------------------
__global__ void vg_face_kernel(const float* __restrict__ pos,
                               const int*   __restrict__ faces,
                               const float* __restrict__ tex,
                               const int*   __restrict__ uvf,
                               float* __restrict__ nacc,
                               float* __restrict__ tacc,
                               int F) {
    int f = blockIdx.x * blockDim.x + threadIdx.x;
    if (f >= F) return;

    const int i0 = faces[3*f+0], i1 = faces[3*f+1], i2 = faces[3*f+2];

    const float p0x = pos[3*i0+0], p0y = pos[3*i0+1], p0z = pos[3*i0+2];
    const float p1x = pos[3*i1+0], p1y = pos[3*i1+1], p1z = pos[3*i1+2];
    const float p2x = pos[3*i2+0], p2y = pos[3*i2+1], p2z = pos[3*i2+2];

    const float e1x = p1x - p0x, e1y = p1y - p0y, e1z = p1z - p0z;
    const float e2x = p2x - p0x, e2y = p2y - p0y, e2z = p2z - p0z;

    const float nx = e1y*e2z - e1z*e2y;
    const float ny = e1z*e2x - e1x*e2z;
    const float nz = e1x*e2y - e1y*e2x;

    const int t0 = uvf[3*f+0], t1 = uvf[3*f+1], t2 = uvf[3*f+2];

    const float u0x = tex[2*t0+0], u0y = tex[2*t0+1];
    const float u1x = tex[2*t1+0], u1y = tex[2*t1+1];
    const float u2x = tex[2*t2+0], u2y = tex[2*t2+1];

    const float d1x = u1x - u0x, d1y = u1y - u0y;
    const float d2x = u2x - u0x, d2y = u2y - u0y;

    float denom = d1x * d2y - d1y * d2x;
    denom = (denom > 0.0f) ? fmaxf(denom, EPS_DENOM) : fminf(denom, -EPS_DENOM);
    const float inv = 1.0f / denom;

    const float tx = (e1x*d2y - e2x*d1y) * inv;
    const float ty = (e1y*d2y - e2y*d1y) * inv;
    const float tz = (e1z*d2y - e2z*d1y) * inv;

    atomicAdd(&nacc[3*i0+0], nx); atomicAdd(&nacc[3*i0+1], ny); atomicAdd(&nacc[3*i0+2], nz);
    atomicAdd(&nacc[3*i1+0], nx); atomicAdd(&nacc[3*i1+1], ny); atomicAdd(&nacc[3*i1+2], nz);
    atomicAdd(&nacc[3*i2+0], nx); atomicAdd(&nacc[3*i2+1], ny); atomicAdd(&nacc[3*i2+2], nz);
    atomicAdd(&tacc[3*i0+0], tx); atomicAdd(&tacc[3*i0+1], ty); atomicAdd(&tacc[3*i0+2], tz);
    atomicAdd(&tacc[3*i1+0], tx); atomicAdd(&tacc[3*i1+1], ty); atomicAdd(&tacc[3*i1+2], tz);
    atomicAdd(&tacc[3*i2+0], tx); atomicAdd(&tacc[3*i2+1], ty); atomicAdd(&tacc[3*i2+2], tz);
}

__global__ void vg_finalize_kernel(float* __restrict__ nacc,
                                   float* __restrict__ tacc,
                                   int V) {
    int v = blockIdx.x * blockDim.x + threadIdx.x;
    if (v >= V) return;

    float nx = nacc[3*v+0], ny = nacc[3*v+1], nz = nacc[3*v+2];
    float nd = nx*nx + ny*ny + nz*nz;
    if (nd > EPS_LEN) {
        const float invn = 1.0f / sqrtf(nd);
        nx *= invn; ny *= invn; nz *= invn;
    } else {
        nx = 0.0f; ny = 0.0f; nz = 1.0f;
    }

    float tx = tacc[3*v+0], ty = tacc[3*v+1], tz = tacc[3*v+2];
    float td = tx*tx + ty*ty + tz*tz;
    float invt = 1.0f / sqrtf(fmaxf(td, EPS_LEN));
    tx *= invt; ty *= invt; tz *= invt;
    const float dp = tx*nx + ty*ny + tz*nz;
    tx -= dp*nx; ty -= dp*ny; tz -= dp*nz;
    float td2 = tx*tx + ty*ty + tz*tz;
    float invt2 = 1.0f / sqrtf(fmaxf(td2, EPS_LEN));
    tx *= invt2; ty *= invt2; tz *= invt2;

    nacc[3*v+0] = nx; nacc[3*v+1] = ny; nacc[3*v+2] = nz;
    tacc[3*v+0] = tx; tacc[3*v+1] = ty; tacc[3*v+2] = tz;
}

extern "C" void kernel_launch(void* const* d_in, const int* in_sizes, int n_in,
                              void* d_out, int out_size, void* d_ws, size_t ws_size,
                              hipStream_t stream) {
    const float* pos   = (const float*)d_in[0];
    const int*   faces = (const int*)  d_in[1];
    const float* tex   = (const float*)d_in[2];
    const int*   uvf   = (const int*)  d_in[3];

    const int V = in_sizes[0] / 3;
    const int F = in_sizes[1] / 3;

    float* out  = (float*)d_out;
    float* nacc = out;
    float* tacc = out + (size_t)3 * V;

    const int NBC = (V + CB - 1) >> CB_LOG;

    const size_t face_bytes = ((size_t)F * FST * sizeof(float) + 255) & ~(size_t)255;
    const size_t ef_bytes   = ((size_t)NBC * CAP_C * sizeof(unsigned) + 255) & ~(size_t)255;
    const size_t ev_bytes   = ((size_t)NBC * CAP_C * sizeof(unsigned short) + 255) & ~(size_t)255;
    const size_t cur_bytes  = (size_t)NBC * sizeof(int);
    const size_t need = face_bytes + ef_bytes + ev_bytes + 2 * cur_bytes + 256;

    hipMemsetAsync(d_out, 0, (size_t)out_size * sizeof(float), stream);

    if (ws_size < need || NBC > 255 || F >= (1 << 22)) {
        const int BLK = 256;
        vg_face_kernel<<<(F + BLK - 1) / BLK, BLK, 0, stream>>>(pos, faces, tex, uvf,
                                                                nacc, tacc, F);
        vg_finalize_kernel<<<(V + BLK - 1) / BLK, BLK, 0, stream>>>(nacc, tacc, V);
        return;
    }

    char* ws = (char*)d_ws;
    float*          face_data = (float*)ws;
    unsigned*       ef        = (unsigned*)(ws + face_bytes);
    unsigned short* ev        = (unsigned short*)(ws + face_bytes + ef_bytes);
    int*            cursors   = (int*)(ws + face_bytes + ef_bytes + ev_bytes);
    int*            validw    = cursors + NBC;

    hipMemsetAsync(cursors, 0, 2 * cur_bytes, stream);

    vg_face_bin<<<(F + BLKA - 1) / BLKA, BLKA, 0, stream>>>(
        pos, faces, tex, uvf, face_data, ef, ev, cursors, validw, nacc, tacc, F, NBC);

    vg_bucket_reduce<<<NBC, BLKA, 0, stream>>>(
        face_data, ef, ev, validw, nacc, tacc, V);
}

// Round 5
// 936.131 us; speedup vs baseline: 3.7822x; 1.0013x over previous
//
#include <hip/hip_runtime.h>

#define EPS_LEN   1e-20f
#define EPS_DENOM 1e-6f

#define CB_LOG   13
#define CB       (1 << CB_LOG)      // 8192 vertices per coarse bucket
#define BLKA     1024
#define MAXB     256
#define CAP1     50176              // tier-1 per-bucket capacity (mean 48980, +5.4 sigma)
#define CAP2     57344              // tier-2 per-bucket capacity (round-3 value)
#define FST      6                  // tier-2 face record floats (24B)
#define QLOG     11
#define QSIZE    (1 << QLOG)
#define VPT      (CB / BLKA)        // vertices per thread in reduce (8)

// ===========================================================================
// TIER 1: entries embed the full f32 payload (numerically identical to ref
// summands). en = face normal (3 f32), et = tangent (3 f32), ev = vloc u16.
// ===========================================================================
__global__ __launch_bounds__(BLKA)
void vg_face_bin_pay(const float* __restrict__ pos, const int* __restrict__ faces,
                     const float* __restrict__ tex, const int* __restrict__ uvf,
                     float* __restrict__ en, float* __restrict__ et,
                     unsigned short* __restrict__ ev,
                     int* __restrict__ cursors, int* __restrict__ validw,
                     float* __restrict__ nacc, float* __restrict__ tacc,
                     int F, int NBC)
{
    __shared__ int h[MAXB], sc[MAXB], loff[MAXB], lfill[MAXB], gbase[MAXB];
    __shared__ float spnx[BLKA], spny[BLKA], spnz[BLKA];
    __shared__ float sptx[BLKA], spty[BLKA], sptz[BLKA];
    __shared__ unsigned short sfl[3 * BLKA];
    __shared__ unsigned short svloc[3 * BLKA];
    __shared__ unsigned char  sbuck[3 * BLKA];

    const int t = threadIdx.x;
    const int f = blockIdx.x * BLKA + t;

    if (t < MAXB) { h[t] = 0; lfill[t] = 0; }
    for (int i = t; i < 3 * BLKA; i += BLKA) sbuck[i] = 0xFF;
    __syncthreads();

    const bool on = (f < F);
    int i0 = 0, i1 = 0, i2 = 0;
    float nx = 0, ny = 0, nz = 0, txv = 0, tyv = 0, tzv = 0;

    if (on) {
        i0 = faces[3 * f + 0]; i1 = faces[3 * f + 1]; i2 = faces[3 * f + 2];

        const float p0x = pos[3*i0+0], p0y = pos[3*i0+1], p0z = pos[3*i0+2];
        const float p1x = pos[3*i1+0], p1y = pos[3*i1+1], p1z = pos[3*i1+2];
        const float p2x = pos[3*i2+0], p2y = pos[3*i2+1], p2z = pos[3*i2+2];

        const float e1x = p1x - p0x, e1y = p1y - p0y, e1z = p1z - p0z;
        const float e2x = p2x - p0x, e2y = p2y - p0y, e2z = p2z - p0z;

        nx = e1y * e2z - e1z * e2y;
        ny = e1z * e2x - e1x * e2z;
        nz = e1x * e2y - e1y * e2x;

        const int t0 = uvf[3 * f + 0];
        const int t1 = uvf[3 * f + 1];
        const int t2 = uvf[3 * f + 2];

        const float u0x = tex[2*t0+0], u0y = tex[2*t0+1];
        const float u1x = tex[2*t1+0], u1y = tex[2*t1+1];
        const float u2x = tex[2*t2+0], u2y = tex[2*t2+1];

        const float d1x = u1x - u0x, d1y = u1y - u0y;
        const float d2x = u2x - u0x, d2y = u2y - u0y;

        float denom = d1x * d2y - d1y * d2x;
        denom = (denom > 0.0f) ? fmaxf(denom, EPS_DENOM) : fminf(denom, -EPS_DENOM);
        const float inv = 1.0f / denom;

        txv = (e1x * d2y - e2x * d1y) * inv;
        tyv = (e1y * d2y - e2y * d1y) * inv;
        tzv = (e1z * d2y - e2z * d1y) * inv;

        spnx[t] = nx;  spny[t] = ny;  spnz[t] = nz;
        sptx[t] = txv; spty[t] = tyv; sptz[t] = tzv;

        atomicAdd(&h[i0 >> CB_LOG], 1);
        atomicAdd(&h[i1 >> CB_LOG], 1);
        atomicAdd(&h[i2 >> CB_LOG], 1);
    }
    __syncthreads();

    // exclusive scan over MAXB (Hillis-Steele)
    if (t < MAXB) sc[t] = h[t];
    __syncthreads();
    for (int d = 1; d < MAXB; d <<= 1) {
        int v2 = 0;
        if (t < MAXB) v2 = sc[t] + ((t >= d) ? sc[t - d] : 0);
        __syncthreads();
        if (t < MAXB) sc[t] = v2;
        __syncthreads();
    }
    if (t < MAXB) {
        loff[t] = sc[t] - h[t];
        const int cnt = h[t];
        int gb = -1;
        if (t < NBC && cnt > 0) {
            gb = atomicAdd(&cursors[t], cnt);
            if (gb + cnt <= CAP1) atomicMax(&validw[t], gb + cnt);
            else gb = -1;                      // whole chunk falls back
        }
        gbase[t] = gb;
    }
    __syncthreads();

    if (on) {
        const int vi[3] = { i0, i1, i2 };
#pragma unroll
        for (int c = 0; c < 3; ++c) {
            const int v = vi[c];
            const int b = v >> CB_LOG;
            if (gbase[b] >= 0) {
                const int slot = atomicAdd(&lfill[b], 1);
                const int p = loff[b] + slot;
                sfl[p]   = (unsigned short)t;
                svloc[p] = (unsigned short)(v & (CB - 1));
                sbuck[p] = (unsigned char)b;
            } else {
                atomicAdd(&nacc[3*v+0], nx);
                atomicAdd(&nacc[3*v+1], ny);
                atomicAdd(&nacc[3*v+2], nz);
                atomicAdd(&tacc[3*v+0], txv);
                atomicAdd(&tacc[3*v+1], tyv);
                atomicAdd(&tacc[3*v+2], tzv);
            }
        }
    }
    __syncthreads();

    // coalesced copy-out: consecutive i in a bucket -> consecutive slots
    for (int i = t; i < 3 * BLKA; i += BLKA) {
        const unsigned b = sbuck[i];
        if (b != 0xFFu) {
            const int g = gbase[b] + (i - loff[b]);
            const size_t s = (size_t)b * CAP1 + g;
            const int fl = sfl[i];
            float* pn = &en[s * 3];
            pn[0] = spnx[fl]; pn[1] = spny[fl]; pn[2] = spnz[fl];
            float* pt = &et[s * 3];
            pt[0] = sptx[fl]; pt[1] = spty[fl]; pt[2] = sptz[fl];
            ev[s] = svloc[i];
        }
    }
}

__global__ __launch_bounds__(BLKA)
void vg_reduce_pay(const float* __restrict__ en, const float* __restrict__ et,
                   const unsigned short* __restrict__ ev,
                   const int* __restrict__ validw,
                   float* __restrict__ nacc, float* __restrict__ tacc,
                   int V)
{
    __shared__ float acc[CB * 3];   // 96 KB
    const int b = blockIdx.x;
    const int t = threadIdx.x;
    int count = validw[b];
    if (count > CAP1) count = CAP1;
    const size_t ebase = (size_t)b * CAP1;
    const int vbase = b << CB_LOG;

    float nreg[VPT][3];

    // ---------------- pass 1: normals ----------------
    for (int i = t; i < CB * 3; i += BLKA) acc[i] = 0.0f;
    __syncthreads();

    for (int e = t; e < count; e += BLKA) {
        const int vloc = (int)ev[ebase + e];
        const float* p = &en[(ebase + e) * 3];
        float* a = &acc[vloc * 3];
        atomicAdd(a + 0, p[0]);
        atomicAdd(a + 1, p[1]);
        atomicAdd(a + 2, p[2]);
    }
    __syncthreads();

#pragma unroll
    for (int k = 0; k < VPT; ++k) {
        const int i = t + k * BLKA;
        const int v = vbase + i;
        float nx = 0.0f, ny = 0.0f, nz = 1.0f;
        if (v < V) {
            nx = nacc[3*v+0] + acc[3*i+0];
            ny = nacc[3*v+1] + acc[3*i+1];
            nz = nacc[3*v+2] + acc[3*i+2];
            const float nd = nx*nx + ny*ny + nz*nz;
            if (nd > EPS_LEN) {
                const float invn = 1.0f / sqrtf(nd);
                nx *= invn; ny *= invn; nz *= invn;
            } else {
                nx = 0.0f; ny = 0.0f; nz = 1.0f;
            }
            nacc[3*v+0] = nx; nacc[3*v+1] = ny; nacc[3*v+2] = nz;
        }
        nreg[k][0] = nx; nreg[k][1] = ny; nreg[k][2] = nz;
    }
    __syncthreads();   // finalize-1 done reading acc before re-zero

    // ---------------- pass 2: tangents ----------------
    for (int i = t; i < CB * 3; i += BLKA) acc[i] = 0.0f;
    __syncthreads();

    for (int e = t; e < count; e += BLKA) {
        const int vloc = (int)ev[ebase + e];
        const float* p = &et[(ebase + e) * 3];
        float* a = &acc[vloc * 3];
        atomicAdd(a + 0, p[0]);
        atomicAdd(a + 1, p[1]);
        atomicAdd(a + 2, p[2]);
    }
    __syncthreads();

#pragma unroll
    for (int k = 0; k < VPT; ++k) {
        const int i = t + k * BLKA;
        const int v = vbase + i;
        if (v < V) {
            float tx = tacc[3*v+0] + acc[3*i+0];
            float ty = tacc[3*v+1] + acc[3*i+1];
            float tz = tacc[3*v+2] + acc[3*i+2];
            const float nx = nreg[k][0], ny = nreg[k][1], nz = nreg[k][2];

            const float td = tx*tx + ty*ty + tz*tz;
            const float invt = 1.0f / sqrtf(fmaxf(td, EPS_LEN));
            tx *= invt; ty *= invt; tz *= invt;

            const float dp = tx*nx + ty*ny + tz*nz;
            tx -= dp * nx; ty -= dp * ny; tz -= dp * nz;

            const float td2 = tx*tx + ty*ty + tz*tz;
            const float invt2 = 1.0f / sqrtf(fmaxf(td2, EPS_LEN));
            tx *= invt2; ty *= invt2; tz *= invt2;

            tacc[3*v+0] = tx; tacc[3*v+1] = ty; tacc[3*v+2] = tz;
        }
    }
}

// ===========================================================================
// TIER 2: round-3 proven path (face-record gather).
// ===========================================================================
__global__ __launch_bounds__(BLKA)
void vg_face_bin3(const float* __restrict__ pos, const int* __restrict__ faces,
                  const float* __restrict__ tex, const int* __restrict__ uvf,
                  float* __restrict__ face_data,
                  unsigned* __restrict__ ef, unsigned short* __restrict__ ev,
                  int* __restrict__ cursors, int* __restrict__ validw,
                  float* __restrict__ nacc, float* __restrict__ tacc,
                  int F, int NBC)
{
    __shared__ int h[MAXB], sc[MAXB], loff[MAXB], lfill[MAXB], gbase[MAXB];
    __shared__ unsigned       sface[3 * BLKA];
    __shared__ unsigned short svloc[3 * BLKA];
    __shared__ unsigned char  sbuck[3 * BLKA];

    const int t = threadIdx.x;
    const int f = blockIdx.x * BLKA + t;

    if (t < MAXB) { h[t] = 0; lfill[t] = 0; }
    for (int i = t; i < 3 * BLKA; i += BLKA) sbuck[i] = 0xFF;
    __syncthreads();

    const bool on = (f < F);
    int i0 = 0, i1 = 0, i2 = 0;
    float nx = 0, ny = 0, nz = 0, txv = 0, tyv = 0, tzv = 0;

    if (on) {
        i0 = faces[3 * f + 0]; i1 = faces[3 * f + 1]; i2 = faces[3 * f + 2];

        const float p0x = pos[3*i0+0], p0y = pos[3*i0+1], p0z = pos[3*i0+2];
        const float p1x = pos[3*i1+0], p1y = pos[3*i1+1], p1z = pos[3*i1+2];
        const float p2x = pos[3*i2+0], p2y = pos[3*i2+1], p2z = pos[3*i2+2];

        const float e1x = p1x - p0x, e1y = p1y - p0y, e1z = p1z - p0z;
        const float e2x = p2x - p0x, e2y = p2y - p0y, e2z = p2z - p0z;

        nx = e1y * e2z - e1z * e2y;
        ny = e1z * e2x - e1x * e2z;
        nz = e1x * e2y - e1y * e2x;

        const int t0 = uvf[3 * f + 0];
        const int t1 = uvf[3 * f + 1];
        const int t2 = uvf[3 * f + 2];

        const float u0x = tex[2*t0+0], u0y = tex[2*t0+1];
        const float u1x = tex[2*t1+0], u1y = tex[2*t1+1];
        const float u2x = tex[2*t2+0], u2y = tex[2*t2+1];

        const float d1x = u1x - u0x, d1y = u1y - u0y;
        const float d2x = u2x - u0x, d2y = u2y - u0y;

        float denom = d1x * d2y - d1y * d2x;
        denom = (denom > 0.0f) ? fmaxf(denom, EPS_DENOM) : fminf(denom, -EPS_DENOM);
        const float inv = 1.0f / denom;

        txv = (e1x * d2y - e2x * d1y) * inv;
        tyv = (e1y * d2y - e2y * d1y) * inv;
        tzv = (e1z * d2y - e2z * d1y) * inv;

        float* fd = &face_data[(size_t)f * FST];
        reinterpret_cast<float2*>(fd)[0] = make_float2(nx, ny);
        reinterpret_cast<float2*>(fd)[1] = make_float2(nz, txv);
        reinterpret_cast<float2*>(fd)[2] = make_float2(tyv, tzv);

        atomicAdd(&h[i0 >> CB_LOG], 1);
        atomicAdd(&h[i1 >> CB_LOG], 1);
        atomicAdd(&h[i2 >> CB_LOG], 1);
    }
    __syncthreads();

    if (t < MAXB) sc[t] = h[t];
    __syncthreads();
    for (int d = 1; d < MAXB; d <<= 1) {
        int v2 = 0;
        if (t < MAXB) v2 = sc[t] + ((t >= d) ? sc[t - d] : 0);
        __syncthreads();
        if (t < MAXB) sc[t] = v2;
        __syncthreads();
    }
    if (t < MAXB) {
        loff[t] = sc[t] - h[t];
        const int cnt = h[t];
        int gb = -1;
        if (t < NBC && cnt > 0) {
            gb = atomicAdd(&cursors[t], cnt);
            if (gb + cnt <= CAP2) atomicMax(&validw[t], gb + cnt);
            else gb = -1;
        }
        gbase[t] = gb;
    }
    __syncthreads();

    if (on) {
        const int vi[3] = { i0, i1, i2 };
#pragma unroll
        for (int c = 0; c < 3; ++c) {
            const int v = vi[c];
            const int b = v >> CB_LOG;
            if (gbase[b] >= 0) {
                const int slot = atomicAdd(&lfill[b], 1);
                const int p = loff[b] + slot;
                sface[p] = (unsigned)f;
                svloc[p] = (unsigned short)(v & (CB - 1));
                sbuck[p] = (unsigned char)b;
            } else {
                atomicAdd(&nacc[3*v+0], nx);
                atomicAdd(&nacc[3*v+1], ny);
                atomicAdd(&nacc[3*v+2], nz);
                atomicAdd(&tacc[3*v+0], txv);
                atomicAdd(&tacc[3*v+1], tyv);
                atomicAdd(&tacc[3*v+2], tzv);
            }
        }
    }
    __syncthreads();

    for (int i = t; i < 3 * BLKA; i += BLKA) {
        const unsigned b = sbuck[i];
        if (b != 0xFFu) {
            const int g = gbase[b] + (i - loff[b]);
            const size_t base = (size_t)b * CAP2;
            ef[base + g] = sface[i];
            ev[base + g] = svloc[i];
        }
    }
}

__global__ __launch_bounds__(BLKA)
void vg_bucket_reduce3(const float* __restrict__ face_data,
                       const unsigned* __restrict__ ef,
                       const unsigned short* __restrict__ ev,
                       const int* __restrict__ validw,
                       float* __restrict__ nacc, float* __restrict__ tacc,
                       int V)
{
    __shared__ float acc[QSIZE * 6];   // 48 KB
    const int b = blockIdx.x;
    const int t = threadIdx.x;
    int count = validw[b];
    if (count > CAP2) count = CAP2;
    const size_t ebase = (size_t)b * CAP2;
    const int vbase = b << CB_LOG;

    for (int q = 0; q < 4; ++q) {
        for (int i = t; i < QSIZE * 6; i += BLKA) acc[i] = 0.0f;
        __syncthreads();

        for (int e = t; e < count; e += BLKA) {
            const int vloc = (int)ev[ebase + e];
            if ((vloc >> QLOG) == q) {
                const unsigned f = ef[ebase + e];
                const float* fd = &face_data[(size_t)f * FST];
                const float2 a0 = reinterpret_cast<const float2*>(fd)[0];
                const float2 a1 = reinterpret_cast<const float2*>(fd)[1];
                const float2 a2 = reinterpret_cast<const float2*>(fd)[2];
                float* a = &acc[(vloc & (QSIZE - 1)) * 6];
                atomicAdd(a + 0, a0.x);
                atomicAdd(a + 1, a0.y);
                atomicAdd(a + 2, a1.x);
                atomicAdd(a + 3, a1.y);
                atomicAdd(a + 4, a2.x);
                atomicAdd(a + 5, a2.y);
            }
        }
        __syncthreads();

        for (int i = t; i < QSIZE; i += BLKA) {
            const int v = vbase + (q << QLOG) + i;
            if (v < V) {
                float nx = nacc[3*v+0] + acc[i*6+0];
                float ny = nacc[3*v+1] + acc[i*6+1];
                float nz = nacc[3*v+2] + acc[i*6+2];
                float tx = tacc[3*v+0] + acc[i*6+3];
                float ty = tacc[3*v+1] + acc[i*6+4];
                float tz = tacc[3*v+2] + acc[i*6+5];

                const float nd = nx*nx + ny*ny + nz*nz;
                if (nd > EPS_LEN) {
                    const float invn = 1.0f / sqrtf(nd);
                    nx *= invn; ny *= invn; nz *= invn;
                } else {
                    nx = 0.0f; ny = 0.0f; nz = 1.0f;
                }

                const float td = tx*tx + ty*ty + tz*tz;
                const float invt = 1.0f / sqrtf(fmaxf(td, EPS_LEN));
                tx *= invt; ty *= invt; tz *= invt;

                const float dp = tx*nx + ty*ny + tz*nz;
                tx -= dp * nx; ty -= dp * ny; tz -= dp * nz;

                const float td2 = tx*tx + ty*ty + tz*tz;
                const float invt2 = 1.0f / sqrtf(fmaxf(td2, EPS_LEN));
                tx *= invt2; ty *= invt2; tz *= invt2;

                nacc[3*v+0] = nx; nacc[3*v+1] = ny; nacc[3*v+2] = nz;
                tacc[3*v+0] = tx; tacc[3*v+1] = ty; tacc[3*v+2] = tz;
            }
        }
        __syncthreads();
    }
}

// ===========================================================================
// TIER 3: round-1 global-atomic fallback.
// ===========================================================================
__global__ void vg_face_kernel(const float* __restrict__ pos,
                               const int*   __restrict__ faces,
                               const float* __restrict__ tex,
                               const int*   __restrict__ uvf,
                               float* __restrict__ nacc,
                               float* __restrict__ tacc,
                               int F) {
    int f = blockIdx.x * blockDim.x + threadIdx.x;
    if (f >= F) return;

    const int i0 = faces[3*f+0], i1 = faces[3*f+1], i2 = faces[3*f+2];

    const float p0x = pos[3*i0+0], p0y = pos[3*i0+1], p0z = pos[3*i0+2];
    const float p1x = pos[3*i1+0], p1y = pos[3*i1+1], p1z = pos[3*i1+2];
    const float p2x = pos[3*i2+0], p2y = pos[3*i2+1], p2z = pos[3*i2+2];

    const float e1x = p1x - p0x, e1y = p1y - p0y, e1z = p1z - p0z;
    const float e2x = p2x - p0x, e2y = p2y - p0y, e2z = p2z - p0z;

    const float nx = e1y*e2z - e1z*e2y;
    const float ny = e1z*e2x - e1x*e2z;
    const float nz = e1x*e2y - e1y*e2x;

    const int t0 = uvf[3*f+0], t1 = uvf[3*f+1], t2 = uvf[3*f+2];

    const float u0x = tex[2*t0+0], u0y = tex[2*t0+1];
    const float u1x = tex[2*t1+0], u1y = tex[2*t1+1];
    const float u2x = tex[2*t2+0], u2y = tex[2*t2+1];

    const float d1x = u1x - u0x, d1y = u1y - u0y;
    const float d2x = u2x - u0x, d2y = u2y - u0y;

    float denom = d1x * d2y - d1y * d2x;
    denom = (denom > 0.0f) ? fmaxf(denom, EPS_DENOM) : fminf(denom, -EPS_DENOM);
    const float inv = 1.0f / denom;

    const float tx = (e1x*d2y - e2x*d1y) * inv;
    const float ty = (e1y*d2y - e2y*d1y) * inv;
    const float tz = (e1z*d2y - e2z*d1y) * inv;

    atomicAdd(&nacc[3*i0+0], nx); atomicAdd(&nacc[3*i0+1], ny); atomicAdd(&nacc[3*i0+2], nz);
    atomicAdd(&nacc[3*i1+0], nx); atomicAdd(&nacc[3*i1+1], ny); atomicAdd(&nacc[3*i1+2], nz);
    atomicAdd(&nacc[3*i2+0], nx); atomicAdd(&nacc[3*i2+1], ny); atomicAdd(&nacc[3*i2+2], nz);
    atomicAdd(&tacc[3*i0+0], tx); atomicAdd(&tacc[3*i0+1], ty); atomicAdd(&tacc[3*i0+2], tz);
    atomicAdd(&tacc[3*i1+0], tx); atomicAdd(&tacc[3*i1+1], ty); atomicAdd(&tacc[3*i1+2], tz);
    atomicAdd(&tacc[3*i2+0], tx); atomicAdd(&tacc[3*i2+1], ty); atomicAdd(&tacc[3*i2+2], tz);
}

__global__ void vg_finalize_kernel(float* __restrict__ nacc,
                                   float* __restrict__ tacc,
                                   int V) {
    int v = blockIdx.x * blockDim.x + threadIdx.x;
    if (v >= V) return;

    float nx = nacc[3*v+0], ny = nacc[3*v+1], nz = nacc[3*v+2];
    float nd = nx*nx + ny*ny + nz*nz;
    if (nd > EPS_LEN) {
        const float invn = 1.0f / sqrtf(nd);
        nx *= invn; ny *= invn; nz *= invn;
    } else {
        nx = 0.0f; ny = 0.0f; nz = 1.0f;
    }

    float tx = tacc[3*v+0], ty = tacc[3*v+1], tz = tacc[3*v+2];
    float td = tx*tx + ty*ty + tz*tz;
    float invt = 1.0f / sqrtf(fmaxf(td, EPS_LEN));
    tx *= invt; ty *= invt; tz *= invt;
    const float dp = tx*nx + ty*ny + tz*nz;
    tx -= dp*nx; ty -= dp*ny; tz -= dp*nz;
    float td2 = tx*tx + ty*ty + tz*tz;
    float invt2 = 1.0f / sqrtf(fmaxf(td2, EPS_LEN));
    tx *= invt2; ty *= invt2; tz *= invt2;

    nacc[3*v+0] = nx; nacc[3*v+1] = ny; nacc[3*v+2] = nz;
    tacc[3*v+0] = tx; tacc[3*v+1] = ty; tacc[3*v+2] = tz;
}

extern "C" void kernel_launch(void* const* d_in, const int* in_sizes, int n_in,
                              void* d_out, int out_size, void* d_ws, size_t ws_size,
                              hipStream_t stream) {
    const float* pos   = (const float*)d_in[0];
    const int*   faces = (const int*)  d_in[1];
    const float* tex   = (const float*)d_in[2];
    const int*   uvf   = (const int*)  d_in[3];

    const int V = in_sizes[0] / 3;
    const int F = in_sizes[1] / 3;

    float* out  = (float*)d_out;
    float* nacc = out;
    float* tacc = out + (size_t)3 * V;

    const int NBC = (V + CB - 1) >> CB_LOG;
    const size_t cur_b = (size_t)NBC * sizeof(int);

    hipMemsetAsync(d_out, 0, (size_t)out_size * sizeof(float), stream);

    // ---- tier 1: embedded-f32 payload ----
    const size_t NE1   = (size_t)NBC * CAP1;
    const size_t en_b  = (NE1 * 12 + 255) & ~(size_t)255;
    const size_t et_b  = (NE1 * 12 + 255) & ~(size_t)255;
    const size_t ev1_b = (NE1 * 2 + 255) & ~(size_t)255;
    const size_t need1 = en_b + et_b + ev1_b + 2 * cur_b + 256;

    if (ws_size >= need1 && NBC <= 255) {
        char* ws = (char*)d_ws;
        float*          en  = (float*)ws;                ws += en_b;
        float*          et  = (float*)ws;                ws += et_b;
        unsigned short* ev  = (unsigned short*)ws;       ws += ev1_b;
        int*            cursors = (int*)ws;
        int*            validw  = cursors + NBC;

        hipMemsetAsync(cursors, 0, 2 * cur_b, stream);

        vg_face_bin_pay<<<(F + BLKA - 1) / BLKA, BLKA, 0, stream>>>(
            pos, faces, tex, uvf, en, et, ev, cursors, validw, nacc, tacc, F, NBC);
        vg_reduce_pay<<<NBC, BLKA, 0, stream>>>(
            en, et, ev, validw, nacc, tacc, V);
        return;
    }

    // ---- tier 2: round-3 face-record gather ----
    const size_t NE2    = (size_t)NBC * CAP2;
    const size_t face_b = ((size_t)F * FST * sizeof(float) + 255) & ~(size_t)255;
    const size_t ef_b   = (NE2 * 4 + 255) & ~(size_t)255;
    const size_t ev2_b  = (NE2 * 2 + 255) & ~(size_t)255;
    const size_t need2  = face_b + ef_b + ev2_b + 2 * cur_b + 256;

    if (ws_size >= need2 && NBC <= 255 && F < (1 << 22)) {
        char* ws = (char*)d_ws;
        float*          face_data = (float*)ws;          ws += face_b;
        unsigned*       ef        = (unsigned*)ws;       ws += ef_b;
        unsigned short* ev        = (unsigned short*)ws; ws += ev2_b;
        int*            cursors   = (int*)ws;
        int*            validw    = cursors + NBC;

        hipMemsetAsync(cursors, 0, 2 * cur_b, stream);

        vg_face_bin3<<<(F + BLKA - 1) / BLKA, BLKA, 0, stream>>>(
            pos, faces, tex, uvf, face_data, ef, ev, cursors, validw,
            nacc, tacc, F, NBC);
        vg_bucket_reduce3<<<NBC, BLKA, 0, stream>>>(
            face_data, ef, ev, validw, nacc, tacc, V);
        return;
    }

    // ---- tier 3: global atomics ----
    const int BLK = 256;
    vg_face_kernel<<<(F + BLK - 1) / BLK, BLK, 0, stream>>>(pos, faces, tex, uvf,
                                                            nacc, tacc, F);
    vg_finalize_kernel<<<(V + BLK - 1) / BLK, BLK, 0, stream>>>(nacc, tacc, V);
}